// Round 3
// baseline (172.619 us; speedup 1.0000x reference)
//
#include <hip/hip_runtime.h>
#include <hip/hip_cooperative_groups.h>

namespace cg = cooperative_groups;

// SwarmNet fused: N=128, T=100, D=4, H=32, Tp=94.
// One cooperative kernel, 384 blocks x 256 threads.
//  Phase A: block = (n = bid/3, third = bid%3). 3-stage conv + ej/ei proj for
//           out t-range [third*31, third*31+32). o-paired register tiles,
//           b128 LDS reads, weights from global (L1-hot).
//  grid.sync()
//  Phase B: block = tile (t = tile>>2, ib = tile&3), tile < 376. Pairwise
//           relu-sum aggregation + Wa/Wu/Wd matmuls + residual.

#define NN 128
#define TT 100
#define TP 94
#define HH 32

union SharedU {
    struct {
        float sx[4][40];    // x cols [t0g, t0g+38)
        float s1[16][44];   // conv1 out, valid cols [0,36)
        float s2[32][40];   // conv2 out, valid cols [0,34) (+garbage to 39)
        float s3[32][32];   // conv3 out, cols [0,32)
    } a;
    struct {
        float sej[NN * HH];
        float sei[32 * HH];
        float sh[32 * HH];
        float sagg[32 * HH];
        float sagg2[32 * HH];
        float supd[32 * HH];
    } b;
};

__global__ __launch_bounds__(256, 2) void k_fused(
    const float* __restrict__ x,
    const float* __restrict__ w1, const float* __restrict__ b1,
    const float* __restrict__ w2, const float* __restrict__ b2,
    const float* __restrict__ w3, const float* __restrict__ b3,
    const float* __restrict__ We, const float* __restrict__ be,
    const float* __restrict__ Wa, const float* __restrict__ ba,
    const float* __restrict__ Wu, const float* __restrict__ bu,
    const float* __restrict__ Wd, const float* __restrict__ bd,
    float* __restrict__ h_g, float* __restrict__ ej_g,
    float* __restrict__ ei_g, float* __restrict__ out)
{
    __shared__ SharedU S;
    const int tid = threadIdx.x;

    // ---------------- Phase A: conv stack ----------------
    {
        const int bid   = blockIdx.x;
        const int n     = bid / 3;
        const int third = bid - n * 3;
        const int t0g   = third * 31;   // out t-range [t0g, t0g+32)

        // stage x: 38 float4 columns
        if (tid < 38) {
            float4 v = ((const float4*)x)[n * TT + t0g + tid];
            S.a.sx[0][tid] = v.x; S.a.sx[1][tid] = v.y;
            S.a.sx[2][tid] = v.z; S.a.sx[3][tid] = v.w;
        }
        __syncthreads();

        // conv1: (4,38) -> (16,36), flat
        for (int idx = tid; idx < 16 * 36; idx += 256) {
            int o = idx / 36, t = idx - o * 36;
            float acc = b1[o];
            #pragma unroll
            for (int i = 0; i < 4; ++i)
                #pragma unroll
                for (int k = 0; k < 3; ++k)
                    acc += S.a.sx[i][t + k] * w1[o * 12 + i * 3 + k];
            S.a.s1[o][t] = fmaxf(acc, 0.f);
        }
        __syncthreads();

        // conv2: (16,36) -> (32,34). thread = (o in 16, seg<5), 2 o x 8 t
        {
            const int o = tid & 15, seg = tid >> 4;
            if (seg < 5) {
                const int t0 = seg * 8;
                float acc0[8], acc1[8];
                float bv0 = b2[o], bv1 = b2[o + 16];
                #pragma unroll
                for (int u = 0; u < 8; ++u) { acc0[u] = bv0; acc1[u] = bv1; }
                #pragma unroll
                for (int i = 0; i < 16; ++i) {
                    float4 f0 = *(const float4*)&S.a.s1[i][t0];
                    float4 f1 = *(const float4*)&S.a.s1[i][t0 + 4];
                    float4 f2 = *(const float4*)&S.a.s1[i][t0 + 8];
                    float a[12] = {f0.x, f0.y, f0.z, f0.w, f1.x, f1.y, f1.z,
                                   f1.w, f2.x, f2.y, f2.z, f2.w};
                    float W00 = w2[o * 48 + i * 3 + 0];
                    float W01 = w2[o * 48 + i * 3 + 1];
                    float W02 = w2[o * 48 + i * 3 + 2];
                    float W10 = w2[(o + 16) * 48 + i * 3 + 0];
                    float W11 = w2[(o + 16) * 48 + i * 3 + 1];
                    float W12 = w2[(o + 16) * 48 + i * 3 + 2];
                    #pragma unroll
                    for (int u = 0; u < 8; ++u) {
                        acc0[u] += a[u] * W00 + a[u + 1] * W01 + a[u + 2] * W02;
                        acc1[u] += a[u] * W10 + a[u + 1] * W11 + a[u + 2] * W12;
                    }
                }
                #pragma unroll
                for (int u = 0; u < 8; ++u) {
                    S.a.s2[o][t0 + u]      = fmaxf(acc0[u], 0.f);
                    S.a.s2[o + 16][t0 + u] = fmaxf(acc1[u], 0.f);
                }
            }
        }
        __syncthreads();

        // conv3: (32,34) -> (32,32). thread = (o in 16, seg<4), 2 o x 8 t
        {
            const int o = tid & 15, seg = tid >> 4;
            if (seg < 4) {
                const int t0 = seg * 8;
                float acc0[8], acc1[8];
                float bv0 = b3[o], bv1 = b3[o + 16];
                #pragma unroll
                for (int u = 0; u < 8; ++u) { acc0[u] = bv0; acc1[u] = bv1; }
                #pragma unroll
                for (int i = 0; i < 32; ++i) {
                    float4 f0 = *(const float4*)&S.a.s2[i][t0];
                    float4 f1 = *(const float4*)&S.a.s2[i][t0 + 4];
                    float4 f2 = *(const float4*)&S.a.s2[i][t0 + 8];
                    float a[12] = {f0.x, f0.y, f0.z, f0.w, f1.x, f1.y, f1.z,
                                   f1.w, f2.x, f2.y, f2.z, f2.w};
                    float W00 = w3[o * 96 + i * 3 + 0];
                    float W01 = w3[o * 96 + i * 3 + 1];
                    float W02 = w3[o * 96 + i * 3 + 2];
                    float W10 = w3[(o + 16) * 96 + i * 3 + 0];
                    float W11 = w3[(o + 16) * 96 + i * 3 + 1];
                    float W12 = w3[(o + 16) * 96 + i * 3 + 2];
                    #pragma unroll
                    for (int u = 0; u < 8; ++u) {
                        acc0[u] += a[u] * W00 + a[u + 1] * W01 + a[u + 2] * W02;
                        acc1[u] += a[u] * W10 + a[u + 1] * W11 + a[u + 2] * W12;
                    }
                }
                #pragma unroll
                for (int u = 0; u < 8; ++u) {
                    S.a.s3[o][t0 + u]      = fmaxf(acc0[u], 0.f);
                    S.a.s3[o + 16][t0 + u] = fmaxf(acc1[u], 0.f);
                }
            }
        }
        __syncthreads();

        // h store: s3 -> h_g[t][n][o], coalesced flat
        for (int idx = tid; idx < 32 * 32; idx += 256) {
            int tl = idx >> 5, o = idx & 31;
            h_g[((t0g + tl) * NN + n) * HH + o] = S.a.s3[o][tl];
        }

        // proj: ej = h@We[:32], ei = h@We[32:]. thread = (d in 32, seg<4), 8 t
        {
            const int d = tid & 31, seg = tid >> 5;
            if (seg < 4) {
                const int t0 = seg * 8;
                float aj[8], ai[8];
                #pragma unroll
                for (int u = 0; u < 8; ++u) { aj[u] = 0.f; ai[u] = 0.f; }
                #pragma unroll
                for (int c = 0; c < 32; ++c) {
                    float4 f0 = *(const float4*)&S.a.s3[c][t0];
                    float4 f1 = *(const float4*)&S.a.s3[c][t0 + 4];
                    float hv[8] = {f0.x, f0.y, f0.z, f0.w, f1.x, f1.y, f1.z, f1.w};
                    float wj = We[c * 32 + d];
                    float wi = We[(32 + c) * 32 + d];
                    #pragma unroll
                    for (int u = 0; u < 8; ++u) {
                        aj[u] += hv[u] * wj;
                        ai[u] += hv[u] * wi;
                    }
                }
                #pragma unroll
                for (int u = 0; u < 8; ++u) {
                    int tg = t0g + t0 + u;
                    ej_g[(tg * NN + n) * HH + d] = aj[u];
                    ei_g[(tg * NN + n) * HH + d] = ai[u];
                }
            }
        }
    }

    cg::this_grid().sync();

    // ---------------- Phase B: aggregation + MLPs ----------------
    {
        const int tile = blockIdx.x;
        if (tile < TP * 4) {
            const int t  = tile >> 2;
            const int ib = tile & 3;

            {
                const float4* ej4 = (const float4*)(ej_g + t * NN * HH);
                float4* s4 = (float4*)S.b.sej;
                #pragma unroll
                for (int u = 0; u < 4; ++u) s4[tid + 256 * u] = ej4[tid + 256 * u];
                const float4* ei4 = (const float4*)(ei_g + (t * NN + ib * 32) * HH);
                const float4* h4  = (const float4*)(h_g  + (t * NN + ib * 32) * HH);
                ((float4*)S.b.sei)[tid] = ei4[tid];
                ((float4*)S.b.sh)[tid]  = h4[tid];
            }
            __syncthreads();

            const int d  = tid & 31;
            const int i0 = tid >> 5;  // thread owns i = i0 + 8u, u<4

            // agg[i,d] = sum_j relu(ej[j,d] + ei[i,d] + be[d]) - diag
            {
                float bev = be[d];
                float c[4], acc[4];
                #pragma unroll
                for (int u = 0; u < 4; ++u) {
                    int i = i0 + u * 8;
                    c[u] = S.b.sei[i * HH + d] + bev;
                    acc[u] = -fmaxf(S.b.sej[(ib * 32 + i) * HH + d] + c[u], 0.f);
                }
                #pragma unroll 8
                for (int j = 0; j < NN; ++j) {
                    float v = S.b.sej[j * HH + d];
                    #pragma unroll
                    for (int u = 0; u < 4; ++u)
                        acc[u] += fmaxf(v + c[u], 0.f);
                }
                #pragma unroll
                for (int u = 0; u < 4; ++u)
                    S.b.sagg[(i0 + u * 8) * HH + d] = acc[u];
            }
            __syncthreads();

            // agg2 = relu(agg @ Wa + ba)
            {
                float acc[4];
                float bav = ba[d];
                #pragma unroll
                for (int u = 0; u < 4; ++u) acc[u] = bav;
                #pragma unroll
                for (int c = 0; c < 32; ++c) {
                    float wa = Wa[c * 32 + d];
                    #pragma unroll
                    for (int u = 0; u < 4; ++u)
                        acc[u] += S.b.sagg[(i0 + u * 8) * HH + c] * wa;
                }
                #pragma unroll
                for (int u = 0; u < 4; ++u)
                    S.b.sagg2[(i0 + u * 8) * HH + d] = fmaxf(acc[u], 0.f);
            }
            __syncthreads();

            // upd = relu(h @ Wu[:32] + agg2 @ Wu[32:] + bu)
            {
                float acc[4];
                float buv = bu[d];
                #pragma unroll
                for (int u = 0; u < 4; ++u) acc[u] = buv;
                #pragma unroll
                for (int c = 0; c < 32; ++c) {
                    float wh = Wu[c * 32 + d];
                    float wg = Wu[(32 + c) * 32 + d];
                    #pragma unroll
                    for (int u = 0; u < 4; ++u) {
                        int i = i0 + u * 8;
                        acc[u] += S.b.sh[i * HH + c] * wh + S.b.sagg2[i * HH + c] * wg;
                    }
                }
                #pragma unroll
                for (int u = 0; u < 4; ++u)
                    S.b.supd[(i0 + u * 8) * HH + d] = fmaxf(acc[u], 0.f);
            }
            __syncthreads();

            // dec = upd @ Wd + bd; out[n,t,:] = x[n,6+t,:] + dec
            if (tid < 128) {
                int i = tid >> 2, d4 = tid & 3;
                int n = ib * 32 + i;
                float a = bd[d4];
                #pragma unroll
                for (int c = 0; c < 32; ++c)
                    a += S.b.supd[i * HH + c] * Wd[c * 4 + d4];
                out[n * (TP * 4) + t * 4 + d4] = x[n * (TT * 4) + (6 + t) * 4 + d4] + a;
            }
        }
    }
}

extern "C" void kernel_launch(void* const* d_in, const int* in_sizes, int n_in,
                              void* d_out, int out_size, void* d_ws, size_t ws_size,
                              hipStream_t stream) {
    const float* x  = (const float*)d_in[0];
    const float* w1 = (const float*)d_in[1];
    const float* b1 = (const float*)d_in[2];
    const float* w2 = (const float*)d_in[3];
    const float* b2 = (const float*)d_in[4];
    const float* w3 = (const float*)d_in[5];
    const float* b3 = (const float*)d_in[6];
    const float* We = (const float*)d_in[7];
    const float* be = (const float*)d_in[8];
    const float* Wa = (const float*)d_in[9];
    const float* ba = (const float*)d_in[10];
    const float* Wu = (const float*)d_in[11];
    const float* bu = (const float*)d_in[12];
    const float* Wd = (const float*)d_in[13];
    const float* bd = (const float*)d_in[14];

    float* ws   = (float*)d_ws;
    float* h_g  = ws;                      // 94*128*32
    float* ej_g = ws + TP * NN * HH;       // 94*128*32
    float* ei_g = ws + 2 * TP * NN * HH;   // 94*128*32
    float* outp = (float*)d_out;

    void* kargs[] = {
        (void*)&x,  (void*)&w1, (void*)&b1, (void*)&w2, (void*)&b2,
        (void*)&w3, (void*)&b3, (void*)&We, (void*)&be, (void*)&Wa,
        (void*)&ba, (void*)&Wu, (void*)&bu, (void*)&Wd, (void*)&bd,
        (void*)&h_g, (void*)&ej_g, (void*)&ei_g, (void*)&outp
    };
    hipLaunchCooperativeKernel((const void*)k_fused, dim3(NN * 3), dim3(256),
                               kargs, 0, stream);
}

// Round 4
// 114.026 us; speedup vs baseline: 1.5139x; 1.5139x over previous
//
#include <hip/hip_runtime.h>

// SwarmNet: N=128 samples(=agents), T=100, D=4, H=32, Tp=94.
// k_conv: grid (128, 4). Block = (sample n, t-quarter q). 3-stage conv + ej/ei
//   proj for out t-range [q*24, q*24+W), W=24 (22 for q=3). Small LDS tiles
//   (9.7 KB), b128 activation reads, weights from global (L2-hot), h written
//   directly from conv3 registers (no LDS transpose -> no bank conflicts).
// k_agg: grid (94, 4). Pairwise relu-sum aggregation + Wa/Wu/Wd matmuls + residual.

#define NN 128
#define TT 100
#define TP 94
#define HH 32

__global__ __launch_bounds__(256) void k_conv(
    const float* __restrict__ x,
    const float* __restrict__ w1, const float* __restrict__ b1,
    const float* __restrict__ w2, const float* __restrict__ b2,
    const float* __restrict__ w3, const float* __restrict__ b3,
    const float* __restrict__ We,
    float* __restrict__ h_g, float* __restrict__ ej_g, float* __restrict__ ei_g)
{
    __shared__ float sx[4][32];    // x cols [t0g, t0g+30), zero-padded
    __shared__ float s1[16][32];   // conv1 out, valid cols [0,28)
    __shared__ float s2[32][32];   // conv2 out, valid cols [0,26)
    __shared__ float s3[32][24];   // conv3 out, valid cols [0,W)

    const int n   = blockIdx.x;
    const int q   = blockIdx.y;
    const int t0g = q * 24;                 // out t-range [t0g, t0g+W)
    const int W   = (q < 3) ? 24 : 22;
    const int tid = threadIdx.x;

    // stage x: 30 float4 columns, guarded
    if (tid < 30) {
        float4 v = make_float4(0.f, 0.f, 0.f, 0.f);
        if (t0g + tid < TT) v = ((const float4*)x)[n * TT + t0g + tid];
        sx[0][tid] = v.x; sx[1][tid] = v.y; sx[2][tid] = v.z; sx[3][tid] = v.w;
    }
    __syncthreads();

    // conv1: (4,30) -> (16,28), flat over 448 outputs
    for (int idx = tid; idx < 16 * 28; idx += 256) {
        int o = idx / 28, t = idx - o * 28;
        float acc = b1[o];
        #pragma unroll
        for (int i = 0; i < 4; ++i)
            #pragma unroll
            for (int k = 0; k < 3; ++k)
                acc += sx[i][t + k] * w1[o * 12 + i * 3 + k];
        s1[o][t] = fmaxf(acc, 0.f);
    }
    __syncthreads();

    // conv2: (16,28) -> (32,26). thread = (o=tid&31, seg=tid>>5 <3), 8 t each
    {
        const int o = tid & 31, seg = tid >> 5;
        if (seg < 3) {
            const int t0 = seg * 8;
            float acc[8];
            float bv = b2[o];
            #pragma unroll
            for (int u = 0; u < 8; ++u) acc[u] = bv;
            #pragma unroll
            for (int i = 0; i < 16; ++i) {
                float4 f0 = *(const float4*)&s1[i][t0];
                float4 f1 = *(const float4*)&s1[i][t0 + 4];
                float4 f2 = *(const float4*)&s1[i][t0 + 8];
                float a[12] = {f0.x, f0.y, f0.z, f0.w, f1.x, f1.y, f1.z, f1.w,
                               f2.x, f2.y, f2.z, f2.w};
                float W0 = w2[o * 48 + i * 3 + 0];
                float W1 = w2[o * 48 + i * 3 + 1];
                float W2 = w2[o * 48 + i * 3 + 2];
                #pragma unroll
                for (int u = 0; u < 8; ++u)
                    acc[u] += a[u] * W0 + a[u + 1] * W1 + a[u + 2] * W2;
            }
            #pragma unroll
            for (int u = 0; u < 8; ++u) s2[o][t0 + u] = fmaxf(acc[u], 0.f);
        }
    }
    __syncthreads();

    // conv3: (32,26) -> (32,W). thread = (o=tid&31, seg=tid>>5 <3), 8 t each.
    // Stores s3 (LDS, zero-padded past W) and h_g directly (coalesced segments).
    {
        const int o = tid & 31, seg = tid >> 5;
        if (seg < 3) {
            const int t0 = seg * 8;
            float acc[8];
            float bv = b3[o];
            #pragma unroll
            for (int u = 0; u < 8; ++u) acc[u] = bv;
            #pragma unroll
            for (int i = 0; i < 32; ++i) {
                float4 f0 = *(const float4*)&s2[i][t0];
                float4 f1 = *(const float4*)&s2[i][t0 + 4];
                float4 f2 = *(const float4*)&s2[i][t0 + 8];
                float a[12] = {f0.x, f0.y, f0.z, f0.w, f1.x, f1.y, f1.z, f1.w,
                               f2.x, f2.y, f2.z, f2.w};
                float W0 = w3[o * 96 + i * 3 + 0];
                float W1 = w3[o * 96 + i * 3 + 1];
                float W2 = w3[o * 96 + i * 3 + 2];
                #pragma unroll
                for (int u = 0; u < 8; ++u)
                    acc[u] += a[u] * W0 + a[u + 1] * W1 + a[u + 2] * W2;
            }
            #pragma unroll
            for (int u = 0; u < 8; ++u) {
                int t = t0 + u;
                float v = (t < W) ? fmaxf(acc[u], 0.f) : 0.f;
                s3[o][t] = v;
                if (t < W) h_g[((t0g + t) * NN + n) * HH + o] = v;
            }
        }
    }
    __syncthreads();

    // proj: ej = h@We[:32], ei = h@We[32:]. thread = (d=tid&31, seg=tid>>5 <3)
    {
        const int d = tid & 31, seg = tid >> 5;
        if (seg < 3) {
            const int t0 = seg * 8;
            float aj[8], ai[8];
            #pragma unroll
            for (int u = 0; u < 8; ++u) { aj[u] = 0.f; ai[u] = 0.f; }
            #pragma unroll
            for (int c = 0; c < 32; ++c) {
                float4 f0 = *(const float4*)&s3[c][t0];
                float4 f1 = *(const float4*)&s3[c][t0 + 4];
                float hv[8] = {f0.x, f0.y, f0.z, f0.w, f1.x, f1.y, f1.z, f1.w};
                float wj = We[c * 32 + d];
                float wi = We[(32 + c) * 32 + d];
                #pragma unroll
                for (int u = 0; u < 8; ++u) {
                    aj[u] += hv[u] * wj;
                    ai[u] += hv[u] * wi;
                }
            }
            #pragma unroll
            for (int u = 0; u < 8; ++u) {
                int t = t0 + u;
                if (t < W) {
                    int tg = t0g + t;
                    ej_g[(tg * NN + n) * HH + d] = aj[u];
                    ei_g[(tg * NN + n) * HH + d] = ai[u];
                }
            }
        }
    }
}

__global__ __launch_bounds__(256) void k_agg(
    const float* __restrict__ x,
    const float* __restrict__ h_g, const float* __restrict__ ej_g,
    const float* __restrict__ ei_g,
    const float* __restrict__ be, const float* __restrict__ Wa,
    const float* __restrict__ ba, const float* __restrict__ Wu,
    const float* __restrict__ bu, const float* __restrict__ Wd,
    const float* __restrict__ bd, float* __restrict__ out)
{
    const int t  = blockIdx.x;  // 0..93
    const int ib = blockIdx.y;  // 0..3 (i-slice of 32 agents)
    const int tid = threadIdx.x;

    __shared__ float sej[NN * HH];
    __shared__ float sei[32 * HH];
    __shared__ float sh[32 * HH];
    __shared__ float sagg[32 * HH];
    __shared__ float sagg2[32 * HH];
    __shared__ float supd[32 * HH];

    // stage ej[t,:,:] (16 KB) + ei/h slices, vectorized
    {
        const float4* ej4 = (const float4*)(ej_g + t * NN * HH);
        float4* s4 = (float4*)sej;
        #pragma unroll
        for (int u = 0; u < 4; ++u) s4[tid + 256 * u] = ej4[tid + 256 * u];
        const float4* ei4 = (const float4*)(ei_g + (t * NN + ib * 32) * HH);
        const float4* h4  = (const float4*)(h_g  + (t * NN + ib * 32) * HH);
        ((float4*)sei)[tid] = ei4[tid];
        ((float4*)sh)[tid]  = h4[tid];
    }
    __syncthreads();

    const int d  = tid & 31;
    const int i0 = tid >> 5;  // thread owns i = i0 + 8u, u<4

    // agg[i,d] = sum_j relu(ej[j,d] + ei[i,d] + be[d]) - diag
    {
        float bev = be[d];
        float c[4], acc[4];
        #pragma unroll
        for (int u = 0; u < 4; ++u) {
            int i = i0 + u * 8;
            c[u] = sei[i * HH + d] + bev;
            acc[u] = -fmaxf(sej[(ib * 32 + i) * HH + d] + c[u], 0.f);
        }
        #pragma unroll 8
        for (int j = 0; j < NN; ++j) {
            float v = sej[j * HH + d];   // broadcast across lanes sharing d
            #pragma unroll
            for (int u = 0; u < 4; ++u)
                acc[u] += fmaxf(v + c[u], 0.f);
        }
        #pragma unroll
        for (int u = 0; u < 4; ++u)
            sagg[(i0 + u * 8) * HH + d] = acc[u];
    }
    __syncthreads();

    // agg2 = relu(agg @ Wa + ba)
    {
        float acc[4];
        float bav = ba[d];
        #pragma unroll
        for (int u = 0; u < 4; ++u) acc[u] = bav;
        #pragma unroll
        for (int c = 0; c < 32; ++c) {
            float wa = Wa[c * 32 + d];
            #pragma unroll
            for (int u = 0; u < 4; ++u)
                acc[u] += sagg[(i0 + u * 8) * HH + c] * wa;
        }
        #pragma unroll
        for (int u = 0; u < 4; ++u)
            sagg2[(i0 + u * 8) * HH + d] = fmaxf(acc[u], 0.f);
    }
    __syncthreads();

    // upd = relu(h @ Wu[:32] + agg2 @ Wu[32:] + bu)
    {
        float acc[4];
        float buv = bu[d];
        #pragma unroll
        for (int u = 0; u < 4; ++u) acc[u] = buv;
        #pragma unroll
        for (int c = 0; c < 32; ++c) {
            float wh = Wu[c * 32 + d];
            float wg = Wu[(32 + c) * 32 + d];
            #pragma unroll
            for (int u = 0; u < 4; ++u) {
                int i = i0 + u * 8;
                acc[u] += sh[i * HH + c] * wh + sagg2[i * HH + c] * wg;
            }
        }
        #pragma unroll
        for (int u = 0; u < 4; ++u)
            supd[(i0 + u * 8) * HH + d] = fmaxf(acc[u], 0.f);
    }
    __syncthreads();

    // dec = upd @ Wd + bd; out[n,t,:] = x[n,6+t,:] + dec
    if (tid < 128) {
        int i = tid >> 2, d4 = tid & 3;
        int n = ib * 32 + i;
        float a = bd[d4];
        #pragma unroll
        for (int c = 0; c < 32; ++c)
            a += supd[i * HH + c] * Wd[c * 4 + d4];
        out[n * (TP * 4) + t * 4 + d4] = x[n * (TT * 4) + (6 + t) * 4 + d4] + a;
    }
}

extern "C" void kernel_launch(void* const* d_in, const int* in_sizes, int n_in,
                              void* d_out, int out_size, void* d_ws, size_t ws_size,
                              hipStream_t stream) {
    const float* x  = (const float*)d_in[0];
    const float* w1 = (const float*)d_in[1];
    const float* b1 = (const float*)d_in[2];
    const float* w2 = (const float*)d_in[3];
    const float* b2 = (const float*)d_in[4];
    const float* w3 = (const float*)d_in[5];
    const float* b3 = (const float*)d_in[6];
    const float* We = (const float*)d_in[7];
    const float* be = (const float*)d_in[8];
    const float* Wa = (const float*)d_in[9];
    const float* ba = (const float*)d_in[10];
    const float* Wu = (const float*)d_in[11];
    const float* bu = (const float*)d_in[12];
    const float* Wd = (const float*)d_in[13];
    const float* bd = (const float*)d_in[14];

    float* ws   = (float*)d_ws;
    float* h_g  = ws;                      // 94*128*32
    float* ej_g = ws + TP * NN * HH;       // 94*128*32
    float* ei_g = ws + 2 * TP * NN * HH;   // 94*128*32

    k_conv<<<dim3(NN, 4), 256, 0, stream>>>(x, w1, b1, w2, b2, w3, b3, We,
                                            h_g, ej_g, ei_g);
    k_agg<<<dim3(TP, 4), 256, 0, stream>>>(x, h_g, ej_g, ei_g,
                                           be, Wa, ba, Wu, bu, Wd, bd,
                                           (float*)d_out);
}

// Round 5
// 105.107 us; speedup vs baseline: 1.6423x; 1.0849x over previous
//
#include <hip/hip_runtime.h>

// SwarmNet: N=128 samples(=agents), T=100, D=4, H=32, Tp=94.
// k_conv: grid (128, 2). Block = (sample n, t-half). Out t-range
//   [half*46, half*46+48) (halves overlap at 46,47 — double-written, benign).
//   o-paired 4t-seg register tiles, b128 LDS activation reads (conflict-free
//   broadcast pattern), weights from global (L1-hot), h written directly from
//   conv3 registers (no LDS transpose, no bank conflicts).
// k_agg: grid (94, 4). Pairwise relu-sum aggregation + Wa/Wu/Wd matmuls + residual.

#define NN 128
#define TT 100
#define TP 94
#define HH 32

__global__ __launch_bounds__(256) void k_conv(
    const float* __restrict__ x,
    const float* __restrict__ w1, const float* __restrict__ b1,
    const float* __restrict__ w2, const float* __restrict__ b2,
    const float* __restrict__ w3, const float* __restrict__ b3,
    const float* __restrict__ We,
    float* __restrict__ h_g, float* __restrict__ ej_g, float* __restrict__ ei_g)
{
    __shared__ float sx[4][56];    // x cols [t0g, t0g+54)
    __shared__ float s1[16][56];   // conv1 out, valid cols [0,52), pad 52..55 = 0
    __shared__ float s2[32][56];   // conv2 out, cols [0,52) (cols >=50 unused junk)
    __shared__ float s3[32][48];   // conv3 out, cols [0,48)

    const int n    = blockIdx.x;
    const int half = blockIdx.y;
    const int t0g  = half * 46;    // out t-range [t0g, t0g+48)
    const int tid  = threadIdx.x;

    // stage x: 54 float4 columns (always in-bounds: t0g+53 <= 99)
    if (tid < 54) {
        float4 v = ((const float4*)x)[n * TT + t0g + tid];
        sx[0][tid] = v.x; sx[1][tid] = v.y; sx[2][tid] = v.z; sx[3][tid] = v.w;
    }
    // zero s1 halo cols 52..55 (read by conv2's b128/a-window, results unused)
    if (tid >= 64 && tid < 128) {
        int r = tid - 64;
        s1[r >> 2][52 + (r & 3)] = 0.f;
    }
    __syncthreads();

    // conv1: (4,54) -> (16,52), flat over 832 outputs
    for (int idx = tid; idx < 16 * 52; idx += 256) {
        int o = idx / 52, t = idx - o * 52;
        float acc = b1[o];
        #pragma unroll
        for (int i = 0; i < 4; ++i)
            #pragma unroll
            for (int k = 0; k < 3; ++k)
                acc += sx[i][t + k] * w1[o * 12 + i * 3 + k];
        s1[o][t] = fmaxf(acc, 0.f);
    }
    __syncthreads();

    // conv2: (16,52) -> (32,52). thread = (op=tid&15, seg=tid>>4 <13),
    // 2 o-channels (op, op+16) x 4 t. Reads 2 b128 per input channel.
    {
        const int op = tid & 15, seg = tid >> 4;
        if (seg < 13) {
            const int t0 = seg * 4;
            float acc0[4], acc1[4];
            float bv0 = b2[op], bv1 = b2[op + 16];
            #pragma unroll
            for (int u = 0; u < 4; ++u) { acc0[u] = bv0; acc1[u] = bv1; }
            #pragma unroll
            for (int i = 0; i < 16; ++i) {
                float4 f0 = *(const float4*)&s1[i][t0];
                float4 f1 = *(const float4*)&s1[i][t0 + 4];
                float a[6] = {f0.x, f0.y, f0.z, f0.w, f1.x, f1.y};
                float W00 = w2[op * 48 + i * 3 + 0];
                float W01 = w2[op * 48 + i * 3 + 1];
                float W02 = w2[op * 48 + i * 3 + 2];
                float W10 = w2[(op + 16) * 48 + i * 3 + 0];
                float W11 = w2[(op + 16) * 48 + i * 3 + 1];
                float W12 = w2[(op + 16) * 48 + i * 3 + 2];
                #pragma unroll
                for (int u = 0; u < 4; ++u) {
                    acc0[u] += a[u] * W00 + a[u + 1] * W01 + a[u + 2] * W02;
                    acc1[u] += a[u] * W10 + a[u + 1] * W11 + a[u + 2] * W12;
                }
            }
            #pragma unroll
            for (int u = 0; u < 4; ++u) {
                s2[op][t0 + u]      = fmaxf(acc0[u], 0.f);
                s2[op + 16][t0 + u] = fmaxf(acc1[u], 0.f);
            }
        }
    }
    __syncthreads();

    // conv3: (32,52) -> (32,48). thread = (op=tid&15, seg=tid>>4 <12),
    // 2 o x 4 t. Writes s3 (for proj) and h_g directly (coalesced 64B runs).
    {
        const int op = tid & 15, seg = tid >> 4;
        if (seg < 12) {
            const int t0 = seg * 4;
            float acc0[4], acc1[4];
            float bv0 = b3[op], bv1 = b3[op + 16];
            #pragma unroll
            for (int u = 0; u < 4; ++u) { acc0[u] = bv0; acc1[u] = bv1; }
            #pragma unroll
            for (int i = 0; i < 32; ++i) {
                float4 f0 = *(const float4*)&s2[i][t0];
                float4 f1 = *(const float4*)&s2[i][t0 + 4];
                float a[6] = {f0.x, f0.y, f0.z, f0.w, f1.x, f1.y};
                float W00 = w3[op * 96 + i * 3 + 0];
                float W01 = w3[op * 96 + i * 3 + 1];
                float W02 = w3[op * 96 + i * 3 + 2];
                float W10 = w3[(op + 16) * 96 + i * 3 + 0];
                float W11 = w3[(op + 16) * 96 + i * 3 + 1];
                float W12 = w3[(op + 16) * 96 + i * 3 + 2];
                #pragma unroll
                for (int u = 0; u < 4; ++u) {
                    acc0[u] += a[u] * W00 + a[u + 1] * W01 + a[u + 2] * W02;
                    acc1[u] += a[u] * W10 + a[u + 1] * W11 + a[u + 2] * W12;
                }
            }
            #pragma unroll
            for (int u = 0; u < 4; ++u) {
                float v0 = fmaxf(acc0[u], 0.f);
                float v1 = fmaxf(acc1[u], 0.f);
                s3[op][t0 + u]      = v0;
                s3[op + 16][t0 + u] = v1;
                int tg = t0g + t0 + u;
                h_g[(tg * NN + n) * HH + op]      = v0;
                h_g[(tg * NN + n) * HH + op + 16] = v1;
            }
        }
    }
    __syncthreads();

    // proj: ej = h@We[:32], ei = h@We[32:]. thread = (dp=tid&15, seg=tid>>4 <12),
    // 2 d x 4 t. One b128 per input channel (broadcast across dp lanes).
    {
        const int dp = tid & 15, seg = tid >> 4;
        if (seg < 12) {
            const int t0 = seg * 4;
            float aj0[4], ai0[4], aj1[4], ai1[4];
            #pragma unroll
            for (int u = 0; u < 4; ++u) { aj0[u]=0.f; ai0[u]=0.f; aj1[u]=0.f; ai1[u]=0.f; }
            #pragma unroll
            for (int c = 0; c < 32; ++c) {
                float4 f0 = *(const float4*)&s3[c][t0];
                float hv[4] = {f0.x, f0.y, f0.z, f0.w};
                float wj0 = We[c * 32 + dp];
                float wj1 = We[c * 32 + dp + 16];
                float wi0 = We[(32 + c) * 32 + dp];
                float wi1 = We[(32 + c) * 32 + dp + 16];
                #pragma unroll
                for (int u = 0; u < 4; ++u) {
                    aj0[u] += hv[u] * wj0;
                    aj1[u] += hv[u] * wj1;
                    ai0[u] += hv[u] * wi0;
                    ai1[u] += hv[u] * wi1;
                }
            }
            #pragma unroll
            for (int u = 0; u < 4; ++u) {
                int tg = t0g + t0 + u;
                ej_g[(tg * NN + n) * HH + dp]      = aj0[u];
                ej_g[(tg * NN + n) * HH + dp + 16] = aj1[u];
                ei_g[(tg * NN + n) * HH + dp]      = ai0[u];
                ei_g[(tg * NN + n) * HH + dp + 16] = ai1[u];
            }
        }
    }
}

__global__ __launch_bounds__(256) void k_agg(
    const float* __restrict__ x,
    const float* __restrict__ h_g, const float* __restrict__ ej_g,
    const float* __restrict__ ei_g,
    const float* __restrict__ be, const float* __restrict__ Wa,
    const float* __restrict__ ba, const float* __restrict__ Wu,
    const float* __restrict__ bu, const float* __restrict__ Wd,
    const float* __restrict__ bd, float* __restrict__ out)
{
    const int t  = blockIdx.x;  // 0..93
    const int ib = blockIdx.y;  // 0..3 (i-slice of 32 agents)
    const int tid = threadIdx.x;

    __shared__ float sej[NN * HH];
    __shared__ float sei[32 * HH];
    __shared__ float sh[32 * HH];
    __shared__ float sagg[32 * HH];
    __shared__ float sagg2[32 * HH];
    __shared__ float supd[32 * HH];

    // stage ej[t,:,:] (16 KB) + ei/h slices, vectorized
    {
        const float4* ej4 = (const float4*)(ej_g + t * NN * HH);
        float4* s4 = (float4*)sej;
        #pragma unroll
        for (int u = 0; u < 4; ++u) s4[tid + 256 * u] = ej4[tid + 256 * u];
        const float4* ei4 = (const float4*)(ei_g + (t * NN + ib * 32) * HH);
        const float4* h4  = (const float4*)(h_g  + (t * NN + ib * 32) * HH);
        ((float4*)sei)[tid] = ei4[tid];
        ((float4*)sh)[tid]  = h4[tid];
    }
    __syncthreads();

    const int d  = tid & 31;
    const int i0 = tid >> 5;  // thread owns i = i0 + 8u, u<4

    // agg[i,d] = sum_j relu(ej[j,d] + ei[i,d] + be[d]) - diag
    {
        float bev = be[d];
        float c[4], acc[4];
        #pragma unroll
        for (int u = 0; u < 4; ++u) {
            int i = i0 + u * 8;
            c[u] = sei[i * HH + d] + bev;
            acc[u] = -fmaxf(sej[(ib * 32 + i) * HH + d] + c[u], 0.f);
        }
        #pragma unroll 8
        for (int j = 0; j < NN; ++j) {
            float v = sej[j * HH + d];   // broadcast across lanes sharing d
            #pragma unroll
            for (int u = 0; u < 4; ++u)
                acc[u] += fmaxf(v + c[u], 0.f);
        }
        #pragma unroll
        for (int u = 0; u < 4; ++u)
            sagg[(i0 + u * 8) * HH + d] = acc[u];
    }
    __syncthreads();

    // agg2 = relu(agg @ Wa + ba)
    {
        float acc[4];
        float bav = ba[d];
        #pragma unroll
        for (int u = 0; u < 4; ++u) acc[u] = bav;
        #pragma unroll
        for (int c = 0; c < 32; ++c) {
            float wa = Wa[c * 32 + d];
            #pragma unroll
            for (int u = 0; u < 4; ++u)
                acc[u] += sagg[(i0 + u * 8) * HH + c] * wa;
        }
        #pragma unroll
        for (int u = 0; u < 4; ++u)
            sagg2[(i0 + u * 8) * HH + d] = fmaxf(acc[u], 0.f);
    }
    __syncthreads();

    // upd = relu(h @ Wu[:32] + agg2 @ Wu[32:] + bu)
    {
        float acc[4];
        float buv = bu[d];
        #pragma unroll
        for (int u = 0; u < 4; ++u) acc[u] = buv;
        #pragma unroll
        for (int c = 0; c < 32; ++c) {
            float wh = Wu[c * 32 + d];
            float wg = Wu[(32 + c) * 32 + d];
            #pragma unroll
            for (int u = 0; u < 4; ++u) {
                int i = i0 + u * 8;
                acc[u] += sh[i * HH + c] * wh + sagg2[i * HH + c] * wg;
            }
        }
        #pragma unroll
        for (int u = 0; u < 4; ++u)
            supd[(i0 + u * 8) * HH + d] = fmaxf(acc[u], 0.f);
    }
    __syncthreads();

    // dec = upd @ Wd + bd; out[n,t,:] = x[n,6+t,:] + dec
    if (tid < 128) {
        int i = tid >> 2, d4 = tid & 3;
        int n = ib * 32 + i;
        float a = bd[d4];
        #pragma unroll
        for (int c = 0; c < 32; ++c)
            a += supd[i * HH + c] * Wd[c * 4 + d4];
        out[n * (TP * 4) + t * 4 + d4] = x[n * (TT * 4) + (6 + t) * 4 + d4] + a;
    }
}

extern "C" void kernel_launch(void* const* d_in, const int* in_sizes, int n_in,
                              void* d_out, int out_size, void* d_ws, size_t ws_size,
                              hipStream_t stream) {
    const float* x  = (const float*)d_in[0];
    const float* w1 = (const float*)d_in[1];
    const float* b1 = (const float*)d_in[2];
    const float* w2 = (const float*)d_in[3];
    const float* b2 = (const float*)d_in[4];
    const float* w3 = (const float*)d_in[5];
    const float* b3 = (const float*)d_in[6];
    const float* We = (const float*)d_in[7];
    const float* be = (const float*)d_in[8];
    const float* Wa = (const float*)d_in[9];
    const float* ba = (const float*)d_in[10];
    const float* Wu = (const float*)d_in[11];
    const float* bu = (const float*)d_in[12];
    const float* Wd = (const float*)d_in[13];
    const float* bd = (const float*)d_in[14];

    float* ws   = (float*)d_ws;
    float* h_g  = ws;                      // 94*128*32
    float* ej_g = ws + TP * NN * HH;       // 94*128*32
    float* ei_g = ws + 2 * TP * NN * HH;   // 94*128*32

    k_conv<<<dim3(NN, 2), 256, 0, stream>>>(x, w1, b1, w2, b2, w3, b3, We,
                                            h_g, ej_g, ei_g);
    k_agg<<<dim3(TP, 4), 256, 0, stream>>>(x, h_g, ej_g, ei_g,
                                           be, Wa, ba, Wu, bu, Wd, bd,
                                           (float*)d_out);
}